// Round 4
// baseline (440.960 us; speedup 1.0000x reference)
//
#include <hip/hip_runtime.h>

// Causal depthwise conv1d, NHC layout, fp32.
// out[b,t,c] = bias[c] + sum_{k=0..3} w[k,0,c] * x[b, t-3+k, c]
// B=4, T=8192, C=2048, K=4.
//
// Round 4: full-row blocks for DRAM page locality.
//  - Evidence: dur_us invariant across 3 kernels (437/449/436) => bench is
//    dominated by ~330us of harness poison-fills; conv part ~106us vs 85us
//    copy-roofline (537 MB @ 6.29 TB/s). Conv runs at ~5.2 TB/s = 83% of
//    the D2D copy rate for the same read/write mix.
//  - Theory: 256-thread blocks covered only HALF a C-row (4 KB), then
//    jumped 8 KB to the next row -> 4KB-read/4KB-skip streams, row halves
//    split across blocks/XCDs. The 6.5 TB/s fills stream contiguously.
//  - Fix: 512-thread blocks own the FULL row width (C4=512). Each step
//    reads/writes 8 adjacent full rows = 64 KB fully contiguous per block.
//    Register sliding window kept (1.047x read amplification). Occupancy
//    unchanged: 8 waves/block x 2 blocks/CU = 16 waves/CU (~106 VGPR).
//  - MLP kept: next chunk's 8 loads issue BEFORE current chunk's FMAs.

constexpr int B = 4;
constexpr int T = 8192;
constexpr int C = 2048;
constexpr int C4 = C / 4;              // 512 float4 groups per row
constexpr int TCHUNK = 8;              // rows per compute chunk
constexpr int LSTRIP = 64;             // rows per thread
constexpr int NSTEPS = LSTRIP / TCHUNK;  // 8 chunks per strip
constexpr int NSTRIP = T / LSTRIP;     // 128 strips per b
constexpr int BLOCK  = 512;            // one full row of float4 groups

__global__ __launch_bounds__(BLOCK) void causal_conv1d_kernel(
    const float4* __restrict__ x,     // [B*T*C4]
    const float*  __restrict__ w,     // [K,1,C] flat: k*C + c
    const float*  __restrict__ bias,  // [C]
    float4* __restrict__ out)         // [B*T*C4]
{
    const int c4 = threadIdx.x;               // 0..511: full row, coalesced
    const int s  = blockIdx.x & (NSTRIP - 1); // strip index 0..127
    const int b  = blockIdx.x >> 7;           // batch
    const int t0 = s * LSTRIP;

    const float4* xb = x   + (size_t)b * T * C4;
    float4*       ob = out + (size_t)b * T * C4;

    // Per-channel weights (K=4) and bias (40 KB total: cache-resident,
    // broadcast across strips so effectively free after first touch).
    const float4* w4 = (const float4*)w;
    const float4 w0 = w4[0 * C4 + c4];
    const float4 w1 = w4[1 * C4 + c4];
    const float4 w2 = w4[2 * C4 + c4];
    const float4 w3 = w4[3 * C4 + c4];
    const float4 bs = ((const float4*)bias)[c4];

    const float4 zero = make_float4(0.f, 0.f, 0.f, 0.f);

    // Window: rows t-3 .. t+7 relative to current chunk base.
    float4 win[TCHUNK + 3];

    // Prologue: first 11 rows (t0-3 .. t0+7). t0 is block-uniform.
    if (t0 != 0) {
#pragma unroll
        for (int i = 0; i < TCHUNK + 3; ++i)
            win[i] = xb[(size_t)(t0 - 3 + i) * C4 + c4];
    } else {
        win[0] = zero; win[1] = zero; win[2] = zero;
#pragma unroll
        for (int i = 0; i < TCHUNK; ++i)
            win[3 + i] = xb[(size_t)i * C4 + c4];
    }

#pragma unroll
    for (int step = 0; step < NSTEPS; ++step) {
        const int tbase = t0 + step * TCHUNK;

        // Prefetch next chunk's 8 rows BEFORE any FMA on the current chunk.
        float4 nxt[TCHUNK];
        if (step < NSTEPS - 1) {
#pragma unroll
            for (int i = 0; i < TCHUNK; ++i)
                nxt[i] = xb[(size_t)(tbase + TCHUNK + i) * C4 + c4];
        }

        // Compute + store the current 8 outputs from the register window.
#pragma unroll
        for (int j = 0; j < TCHUNK; ++j) {
            const float4 a0 = win[j], a1 = win[j + 1], a2 = win[j + 2], a3 = win[j + 3];
            float4 o;
            o.x = fmaf(w3.x, a3.x, fmaf(w2.x, a2.x, fmaf(w1.x, a1.x, fmaf(w0.x, a0.x, bs.x))));
            o.y = fmaf(w3.y, a3.y, fmaf(w2.y, a2.y, fmaf(w1.y, a1.y, fmaf(w0.y, a0.y, bs.y))));
            o.z = fmaf(w3.z, a3.z, fmaf(w2.z, a2.z, fmaf(w1.z, a1.z, fmaf(w0.z, a0.z, bs.z))));
            o.w = fmaf(w3.w, a3.w, fmaf(w2.w, a2.w, fmaf(w1.w, a1.w, fmaf(w0.w, a0.w, bs.w))));
            ob[(size_t)(tbase + j) * C4 + c4] = o;
        }

        // Slide the window: keep last 3 rows, append the prefetched 8.
        // Outer loop is fully unrolled -> compiler renames, no real moves.
        if (step < NSTEPS - 1) {
            win[0] = win[TCHUNK];
            win[1] = win[TCHUNK + 1];
            win[2] = win[TCHUNK + 2];
#pragma unroll
            for (int i = 0; i < TCHUNK; ++i)
                win[3 + i] = nxt[i];
        }
    }
}

extern "C" void kernel_launch(void* const* d_in, const int* in_sizes, int n_in,
                              void* d_out, int out_size, void* d_ws, size_t ws_size,
                              hipStream_t stream) {
    const float4* x    = (const float4*)d_in[0];
    const float*  w    = (const float*)d_in[1];
    const float*  bias = (const float*)d_in[2];
    float4* out = (float4*)d_out;

    const int grid = B * NSTRIP;                 // 512 blocks = 2/CU exactly
    causal_conv1d_kernel<<<grid, BLOCK, 0, stream>>>(x, w, bias, out);
}